// Round 6
// baseline (230.829 us; speedup 1.0000x reference)
//
#include <hip/hip_runtime.h>
#include <cstdint>

#define B8   8
#define DIN  1024
#define NH1  2048
#define NH2  1024
#define NOUT 5120

__device__ __forceinline__ float4 ld4(const float* p) {
  return *reinterpret_cast<const float4*>(p);
}
__device__ __forceinline__ void st4(float* p, float4 v) {
  *reinterpret_cast<float4*>(p) = v;
}

// C_parts[kb][8][N] = A[8, k0:k0+KC] @ W[k0:k0+KC, :]   (partial over K-chunk)
// A source: raw input (NPART==0) or sum of NPART partials + bias (+ReLU).
// The staged (finalized) A chunk is optionally written out (features).
template<int K, int N, int KSPLIT, int NPART, bool RELU_IN, bool WRITE_STAGE>
__global__ __launch_bounds__(256)
void gemm8(const float* __restrict__ Asrc, const float* __restrict__ bias_in,
           const float* __restrict__ W, float* __restrict__ Cparts,
           float* __restrict__ stage_out)
{
  constexpr int KC    = K / KSPLIT;   // k-chunk per block
  constexpr int KC4   = KC / 4;
  constexpr int NCOLB = N / 64;       // 64 output cols per block
  constexpr int KT    = KC / 16;      // k elements per thread

  __shared__ float A_lds[8][KC];      // <= 8 KB
  __shared__ float red[16][8][64];    // 32 KB

  const int tid = threadIdx.x;
  const int kb  = blockIdx.x / NCOLB;
  const int cb  = blockIdx.x % NCOLB;
  const int k0  = kb * KC;

  // ---- stage A chunk into LDS (finalize previous stage: sum partials + bias + relu)
  for (int e = tid; e < 8 * KC4; e += 256) {
    const int b = e / KC4, k4 = e - b * KC4;
    float4 v;
    if constexpr (NPART == 0) {
      v = ld4(&Asrc[(size_t)b * K + k0 + 4 * k4]);
    } else {
      v = ld4(&bias_in[k0 + 4 * k4]);
      #pragma unroll
      for (int p = 0; p < NPART; ++p) {
        float4 t = ld4(&Asrc[((size_t)p * 8 + b) * K + k0 + 4 * k4]);
        v.x += t.x; v.y += t.y; v.z += t.z; v.w += t.w;
      }
      if constexpr (RELU_IN) {
        v.x = fmaxf(v.x, 0.f); v.y = fmaxf(v.y, 0.f);
        v.z = fmaxf(v.z, 0.f); v.w = fmaxf(v.w, 0.f);
      }
    }
    st4(&A_lds[b][4 * k4], v);
    if constexpr (WRITE_STAGE) {
      if (cb == 0) st4(&stage_out[(size_t)b * K + k0 + 4 * k4], v);
    }
  }
  __syncthreads();

  // ---- main loop: 16 col-groups (float4) x 16 k-slices
  const int g  = tid & 15, ks = tid >> 4;
  const int c0 = cb * 64 + g * 4;
  float4 acc[8];
  #pragma unroll
  for (int b = 0; b < 8; ++b) acc[b] = make_float4(0.f, 0.f, 0.f, 0.f);

  const float* Wp = &W[(size_t)(k0 + ks * KT) * N + c0];
  #pragma unroll
  for (int i = 0; i < KT; i += 4) {
    const float4 w0 = ld4(Wp + (size_t)(i + 0) * N);
    const float4 w1 = ld4(Wp + (size_t)(i + 1) * N);
    const float4 w2 = ld4(Wp + (size_t)(i + 2) * N);
    const float4 w3 = ld4(Wp + (size_t)(i + 3) * N);
    const int kk = ks * KT + i;
    #pragma unroll
    for (int b = 0; b < 8; ++b) {
      const float4 a = ld4(&A_lds[b][kk]);   // broadcast within 16-lane group
      acc[b].x += a.x * w0.x + a.y * w1.x + a.z * w2.x + a.w * w3.x;
      acc[b].y += a.x * w0.y + a.y * w1.y + a.z * w2.y + a.w * w3.y;
      acc[b].z += a.x * w0.z + a.y * w1.z + a.z * w2.z + a.w * w3.z;
      acc[b].w += a.x * w0.w + a.y * w1.w + a.z * w2.w + a.w * w3.w;
    }
  }

  // ---- reduce the 16 k-slices through LDS
  __syncthreads();
  #pragma unroll
  for (int b = 0; b < 8; ++b) st4(&red[ks][b][g * 4], acc[b]);
  __syncthreads();

  for (int p = tid; p < 512; p += 256) {
    const int c = p & 63, b = p >> 6;
    float s = 0.f;
    #pragma unroll
    for (int j = 0; j < 16; ++j) s += red[j][b][c];
    Cparts[((size_t)kb * 8 + b) * N + cb * 64 + c] = s;
  }
}

// logits[8][5120] = sum of 4 partials + b3
__global__ __launch_bounds__(256)
void finalize_logits(const float* __restrict__ parts, const float* __restrict__ b3,
                     float* __restrict__ logits)
{
  const int i  = blockIdx.x * 256 + threadIdx.x;   // 10240 float4s, grid exact
  const int b  = i / 1280, k4 = i - b * 1280;
  float4 v = ld4(&b3[4 * k4]);
  #pragma unroll
  for (int p = 0; p < 4; ++p) {
    const float4 t = ld4(&parts[((size_t)p * 8 + b) * NOUT + 4 * k4]);
    v.x += t.x; v.y += t.y; v.z += t.z; v.w += t.w;
  }
  st4(&logits[(size_t)b * NOUT + 4 * k4], v);
}

// out[b][o] = max_k logits[b][k] * CM[o][k]
// Double-buffered pipeline: LDS [2][8][1024] (64 KB). Per chunk:
//   issue chunk i+1's 16 independent ld4s (8 logits + 8 CM, register-staged)
//   -> compute chunk i from LDS[cur] x cm[cur] (loads in flight under compute)
//   -> vmcnt wait -> ds_write LDS[nxt] -> ONE barrier.
// This removes the vmcnt(0)-before-barrier drain that serialized every
// previous variant (R0-R4 all pinned at ~1 TB/s). 640 blocks x 4 waves,
// 8 CM rows/block (2/wave, each LDS read reused 2x). Thread tid stages
// logits[b=j][4*tid] (e=tid+256j -> b==j, k4==tid).
__global__ __launch_bounds__(256)
void tropical8(const float* __restrict__ logits, const float* __restrict__ CM,
               float* __restrict__ out)
{
  __shared__ float L[2][8][1024];   // 64 KB double buffer

  const int tid = threadIdx.x;
  const int w   = tid >> 6;      // wave 0..3
  const int l   = tid & 63;      // lane
  const int o0  = blockIdx.x * 8 + w * 2;   // this wave's 2 CM rows

  const float* cm0 = &CM[(size_t)(o0 + 0) * NOUT + 4 * l];
  const float* cm1 = &CM[(size_t)(o0 + 1) * NOUT + 4 * l];

  float4 Lreg[8];
  float4 cmb[2][2][4];   // [buf][r][i]
  float  pmax[2][8];
  #pragma unroll
  for (int r = 0; r < 2; ++r)
    #pragma unroll
    for (int b = 0; b < 8; ++b) pmax[r][b] = -3.402823466e38f;

  // ---- prologue: chunk 0
  #pragma unroll
  for (int j = 0; j < 8; ++j) Lreg[j] = ld4(&logits[(size_t)j * NOUT + 4 * tid]);
  #pragma unroll
  for (int i = 0; i < 4; ++i) cmb[0][0][i] = ld4(cm0 + 256 * i);
  #pragma unroll
  for (int i = 0; i < 4; ++i) cmb[0][1][i] = ld4(cm1 + 256 * i);
  #pragma unroll
  for (int j = 0; j < 8; ++j) st4(&L[0][j][4 * tid], Lreg[j]);
  __syncthreads();

  // ---- 5 chunks, fully unrolled (static buffer indices)
  #pragma unroll
  for (int ck = 0; ck < 5; ++ck) {
    const int cur = ck & 1, nxt = cur ^ 1;

    if (ck < 4) {                       // issue next chunk's loads early
      const int off = (ck + 1) * 1024;
      #pragma unroll
      for (int j = 0; j < 8; ++j)
        Lreg[j] = ld4(&logits[(size_t)j * NOUT + off + 4 * tid]);
      #pragma unroll
      for (int i = 0; i < 4; ++i) cmb[nxt][0][i] = ld4(cm0 + off + 256 * i);
      #pragma unroll
      for (int i = 0; i < 4; ++i) cmb[nxt][1][i] = ld4(cm1 + off + 256 * i);
    }

    // compute chunk ck from LDS[cur] x cmb[cur] (next-chunk loads in flight)
    #pragma unroll
    for (int i = 0; i < 4; ++i) {
      const int kk = 4 * l + 256 * i;
      #pragma unroll
      for (int b = 0; b < 8; ++b) {
        const float4 lv = ld4(&L[cur][b][kk]);
        #pragma unroll
        for (int r = 0; r < 2; ++r) {
          const float4 C = cmb[cur][r][i];
          const float m0 = fmaxf(lv.x * C.x, lv.y * C.y);
          const float m1 = fmaxf(lv.z * C.z, lv.w * C.w);
          pmax[r][b] = fmaxf(pmax[r][b], fmaxf(m0, m1));
        }
      }
    }

    if (ck < 4) {                       // write next buffer, single barrier
      #pragma unroll
      for (int j = 0; j < 8; ++j) st4(&L[nxt][j][4 * tid], Lreg[j]);
      __syncthreads();
    }
  }

  // cross-lane max reduce; lane 0 writes
  #pragma unroll
  for (int r = 0; r < 2; ++r) {
    #pragma unroll
    for (int b = 0; b < 8; ++b) {
      float v = pmax[r][b];
      for (int m = 32; m; m >>= 1) v = fmaxf(v, __shfl_xor(v, m));
      if (l == 0) out[(size_t)b * NOUT + o0 + r] = v;
    }
  }
}

extern "C" void kernel_launch(void* const* d_in, const int* in_sizes, int n_in,
                              void* d_out, int out_size, void* d_ws, size_t ws_size,
                              hipStream_t stream)
{
  const float* x  = (const float*)d_in[0];
  const float* W1 = (const float*)d_in[1];
  const float* b1 = (const float*)d_in[2];
  const float* W2 = (const float*)d_in[3];
  const float* b2 = (const float*)d_in[4];
  const float* W3 = (const float*)d_in[5];
  const float* b3 = (const float*)d_in[6];
  const float* CM = (const float*)d_in[7];

  float* out  = (float*)d_out;            // [8][5120]
  float* feat = out + B8 * NOUT;          // [8][1024]

  float* ws      = (float*)d_ws;
  float* parts1  = ws;                      // [ 8][8][2048] = 131072 f
  float* parts2  = parts1 + 8  * 8 * NH1;   // [16][8][1024] = 131072 f
  float* parts3  = parts2 + 16 * 8 * NH2;   // [ 4][8][5120] = 163840 f
  float* logits  = parts3 + 4  * 8 * NOUT;  // [8][5120]     =  40960 f

  // h1 partials: x[8,1024] @ W1[1024,2048], K split 8 -> 256 blocks
  gemm8<DIN, NH1, 8, 0, false, false><<<256, 256, 0, stream>>>(x, nullptr, W1, parts1, nullptr);
  // h2 partials: relu(sum parts1 + b1) @ W2[2048,1024], K split 16 -> 256 blocks
  gemm8<NH1, NH2, 16, 8, true, false><<<256, 256, 0, stream>>>(parts1, b1, W2, parts2, nullptr);
  // logits partials: relu(sum parts2 + b2) @ W3[1024,5120], K split 4 -> 320 blocks
  // (staged A == features; written by cb==0 blocks)
  gemm8<NH2, NOUT, 4, 16, true, true><<<320, 256, 0, stream>>>(parts2, b2, W3, parts3, feat);
  // logits = sum parts3 + b3
  finalize_logits<<<40, 256, 0, stream>>>(parts3, b3, logits);
  // tropical max-product: 640 blocks x 8 rows, double-buffered pipeline
  tropical8<<<640, 256, 0, stream>>>(logits, CM, out);
}

// Round 7
// 71.491 us; speedup vs baseline: 3.2288x; 3.2288x over previous
//
#include <hip/hip_runtime.h>
#include <cstdint>

#define B8   8
#define DIN  1024
#define NH1  2048
#define NH2  1024
#define NOUT 5120
#define KHALF 2560   // tropical k-half
#define ROWS_PER_BLOCK 20

__device__ __forceinline__ float4 ld4(const float* p) {
  return *reinterpret_cast<const float4*>(p);
}
__device__ __forceinline__ void st4(float* p, float4 v) {
  *reinterpret_cast<float4*>(p) = v;
}

// C_parts[kb][8][N] = A[8, k0:k0+KC] @ W[k0:k0+KC, :]   (partial over K-chunk)
// A source: raw input (NPART==0) or sum of NPART partials + bias (+ReLU).
// The staged (finalized) A chunk is optionally written out (features).
template<int K, int N, int KSPLIT, int NPART, bool RELU_IN, bool WRITE_STAGE>
__global__ __launch_bounds__(256)
void gemm8(const float* __restrict__ Asrc, const float* __restrict__ bias_in,
           const float* __restrict__ W, float* __restrict__ Cparts,
           float* __restrict__ stage_out)
{
  constexpr int KC    = K / KSPLIT;   // k-chunk per block
  constexpr int KC4   = KC / 4;
  constexpr int NCOLB = N / 64;       // 64 output cols per block
  constexpr int KT    = KC / 16;      // k elements per thread

  __shared__ float A_lds[8][KC];      // <= 8 KB
  __shared__ float red[16][8][64];    // 32 KB

  const int tid = threadIdx.x;
  const int kb  = blockIdx.x / NCOLB;
  const int cb  = blockIdx.x % NCOLB;
  const int k0  = kb * KC;

  // ---- stage A chunk into LDS (finalize previous stage: sum partials + bias + relu)
  for (int e = tid; e < 8 * KC4; e += 256) {
    const int b = e / KC4, k4 = e - b * KC4;
    float4 v;
    if constexpr (NPART == 0) {
      v = ld4(&Asrc[(size_t)b * K + k0 + 4 * k4]);
    } else {
      v = ld4(&bias_in[k0 + 4 * k4]);
      #pragma unroll
      for (int p = 0; p < NPART; ++p) {
        float4 t = ld4(&Asrc[((size_t)p * 8 + b) * K + k0 + 4 * k4]);
        v.x += t.x; v.y += t.y; v.z += t.z; v.w += t.w;
      }
      if constexpr (RELU_IN) {
        v.x = fmaxf(v.x, 0.f); v.y = fmaxf(v.y, 0.f);
        v.z = fmaxf(v.z, 0.f); v.w = fmaxf(v.w, 0.f);
      }
    }
    st4(&A_lds[b][4 * k4], v);
    if constexpr (WRITE_STAGE) {
      if (cb == 0) st4(&stage_out[(size_t)b * K + k0 + 4 * k4], v);
    }
  }
  __syncthreads();

  // ---- main loop: 16 col-groups (float4) x 16 k-slices
  const int g  = tid & 15, ks = tid >> 4;
  const int c0 = cb * 64 + g * 4;
  float4 acc[8];
  #pragma unroll
  for (int b = 0; b < 8; ++b) acc[b] = make_float4(0.f, 0.f, 0.f, 0.f);

  const float* Wp = &W[(size_t)(k0 + ks * KT) * N + c0];
  #pragma unroll
  for (int i = 0; i < KT; i += 4) {
    const float4 w0 = ld4(Wp + (size_t)(i + 0) * N);
    const float4 w1 = ld4(Wp + (size_t)(i + 1) * N);
    const float4 w2 = ld4(Wp + (size_t)(i + 2) * N);
    const float4 w3 = ld4(Wp + (size_t)(i + 3) * N);
    const int kk = ks * KT + i;
    #pragma unroll
    for (int b = 0; b < 8; ++b) {
      const float4 a = ld4(&A_lds[b][kk]);   // broadcast within 16-lane group
      acc[b].x += a.x * w0.x + a.y * w1.x + a.z * w2.x + a.w * w3.x;
      acc[b].y += a.x * w0.y + a.y * w1.y + a.z * w2.y + a.w * w3.y;
      acc[b].z += a.x * w0.z + a.y * w1.z + a.z * w2.z + a.w * w3.z;
      acc[b].w += a.x * w0.w + a.y * w1.w + a.z * w2.w + a.w * w3.w;
    }
  }

  // ---- reduce the 16 k-slices through LDS
  __syncthreads();
  #pragma unroll
  for (int b = 0; b < 8; ++b) st4(&red[ks][b][g * 4], acc[b]);
  __syncthreads();

  for (int p = tid; p < 512; p += 256) {
    const int c = p & 63, b = p >> 6;
    float s = 0.f;
    #pragma unroll
    for (int j = 0; j < 16; ++j) s += red[j][b][c];
    Cparts[((size_t)kb * 8 + b) * N + cb * 64 + c] = s;
  }
}

// logits[8][5120] = sum of 4 partials + b3
__global__ __launch_bounds__(256)
void finalize_logits(const float* __restrict__ parts, const float* __restrict__ b3,
                     float* __restrict__ logits)
{
  const int i  = blockIdx.x * 256 + threadIdx.x;   // 10240 float4s, grid exact
  const int b  = i / 1280, k4 = i - b * 1280;
  float4 v = ld4(&b3[4 * k4]);
  #pragma unroll
  for (int p = 0; p < 4; ++p) {
    const float4 t = ld4(&parts[((size_t)p * 8 + b) * NOUT + 4 * k4]);
    v.x += t.x; v.y += t.y; v.z += t.z; v.w += t.w;
  }
  st4(&logits[(size_t)b * NOUT + 4 * k4], v);
}

// tpart[kh][b][o] = max_{k in half kh} logits[b][k] * CM[o][k]
// Copy-shaped streaming: ONE barrier (logits->LDS stage), then pure
// free-running per-wave row walk. Grid (256 rowblocks x 2 khalf) = 512
// blocks, 80 KB LDS -> 2 blocks/CU = 8 waves/CU. Each wave owns 5 rows;
// per row: 10 independent 1KB loads (ping-pong reg buffers, 20 float4
// live -- under the spill threshold), LDS-broadcast logits, shfl-max
// reduce, plain stores. No vmcnt(0)-before-barrier in the hot loop.
__global__ __launch_bounds__(256)
void tropical_stream(const float* __restrict__ logits, const float* __restrict__ CM,
                     float* __restrict__ tpart)
{
  __shared__ float L[8][KHALF];   // 80 KB logits half

  const int tid = threadIdx.x;
  const int w   = tid >> 6;       // wave 0..3
  const int l   = tid & 63;       // lane
  const int kh  = blockIdx.y;
  const int k0  = kh * KHALF;

  // ---- stage logits half: 5120 float4s over 256 threads (coalesced)
  for (int e = tid; e < 5120; e += 256) {
    const int b = e / 640, j = e - b * 640;
    st4(&L[b][4 * j], ld4(&logits[(size_t)b * NOUT + k0 + 4 * j]));
  }
  __syncthreads();   // the only barrier

  const int orow0 = blockIdx.x * ROWS_PER_BLOCK + w * 5;   // wave's 5 rows

  float4 A[10], Bv[10];
  const float* row0 = &CM[(size_t)orow0 * NOUT + k0 + 4 * l];
  #pragma unroll
  for (int j = 0; j < 10; ++j) A[j] = ld4(row0 + 256 * j);

  #pragma unroll
  for (int i = 0; i < 5; ++i) {          // full unroll: i is a literal
    // issue next row's 10 independent loads (in flight under compute)
    if (i < 4) {
      const float* rn = &CM[(size_t)(orow0 + i + 1) * NOUT + k0 + 4 * l];
      if (i & 1) {
        #pragma unroll
        for (int j = 0; j < 10; ++j) A[j] = ld4(rn + 256 * j);
      } else {
        #pragma unroll
        for (int j = 0; j < 10; ++j) Bv[j] = ld4(rn + 256 * j);
      }
    }

    // compute current row from the other buffer
    float pmax[8];
    #pragma unroll
    for (int b = 0; b < 8; ++b) pmax[b] = -3.402823466e38f;
    #pragma unroll
    for (int j = 0; j < 10; ++j) {
      const float4 C = (i & 1) ? Bv[j] : A[j];
      const int kk = 4 * (l + 64 * j);
      #pragma unroll
      for (int b = 0; b < 8; ++b) {
        const float4 lv = ld4(&L[b][kk]);
        const float m0 = fmaxf(lv.x * C.x, lv.y * C.y);
        const float m1 = fmaxf(lv.z * C.z, lv.w * C.w);
        pmax[b] = fmaxf(pmax[b], fmaxf(m0, m1));
      }
    }

    // wave max-reduce; lane 0 stores (each (kh,b,o) written exactly once)
    #pragma unroll
    for (int b = 0; b < 8; ++b) {
      float v = pmax[b];
      for (int m = 32; m; m >>= 1) v = fmaxf(v, __shfl_xor(v, m));
      if (l == 0) tpart[((size_t)kh * 8 + b) * NOUT + orow0 + i] = v;
    }
  }
}

// out[b][o] = max_kh tpart[kh][b][o]
__global__ __launch_bounds__(256)
void tropical_combine(const float* __restrict__ tpart, float* __restrict__ out)
{
  const int i = blockIdx.x * 256 + threadIdx.x;   // 10240 float4s, grid exact
  const float4 a = ld4(&tpart[4 * (size_t)i]);
  const float4 b = ld4(&tpart[(size_t)8 * NOUT + 4 * (size_t)i]);
  float4 v;
  v.x = fmaxf(a.x, b.x); v.y = fmaxf(a.y, b.y);
  v.z = fmaxf(a.z, b.z); v.w = fmaxf(a.w, b.w);
  st4(&out[4 * (size_t)i], v);
}

extern "C" void kernel_launch(void* const* d_in, const int* in_sizes, int n_in,
                              void* d_out, int out_size, void* d_ws, size_t ws_size,
                              hipStream_t stream)
{
  const float* x  = (const float*)d_in[0];
  const float* W1 = (const float*)d_in[1];
  const float* b1 = (const float*)d_in[2];
  const float* W2 = (const float*)d_in[3];
  const float* b2 = (const float*)d_in[4];
  const float* W3 = (const float*)d_in[5];
  const float* b3 = (const float*)d_in[6];
  const float* CM = (const float*)d_in[7];

  float* out  = (float*)d_out;            // [8][5120]
  float* feat = out + B8 * NOUT;          // [8][1024]

  float* ws      = (float*)d_ws;
  float* parts1  = ws;                      // [ 8][8][2048] = 131072 f
  float* parts2  = parts1 + 8  * 8 * NH1;   // [16][8][1024] = 131072 f
  float* parts3  = parts2 + 16 * 8 * NH2;   // [ 4][8][5120] = 163840 f
  float* logits  = parts3 + 4  * 8 * NOUT;  // [8][5120]     =  40960 f
  float* tpart   = logits + 8 * NOUT;       // [2][8][5120]  =  81920 f

  // h1 partials: x[8,1024] @ W1[1024,2048], K split 8 -> 256 blocks
  gemm8<DIN, NH1, 8, 0, false, false><<<256, 256, 0, stream>>>(x, nullptr, W1, parts1, nullptr);
  // h2 partials: relu(sum parts1 + b1) @ W2[2048,1024], K split 16 -> 256 blocks
  gemm8<NH1, NH2, 16, 8, true, false><<<256, 256, 0, stream>>>(parts1, b1, W2, parts2, nullptr);
  // logits partials: relu(sum parts2 + b2) @ W3[1024,5120], K split 4 -> 320 blocks
  // (staged A == features; written by cb==0 blocks)
  gemm8<NH2, NOUT, 4, 16, true, true><<<320, 256, 0, stream>>>(parts2, b2, W3, parts3, feat);
  // logits = sum parts3 + b3
  finalize_logits<<<40, 256, 0, stream>>>(parts3, b3, logits);
  // tropical: 256 rowblocks x 2 khalves, copy-shaped streaming
  {
    dim3 grid(256, 2);
    tropical_stream<<<grid, 256, 0, stream>>>(logits, CM, tpart);
  }
  // fold the two k-halves
  tropical_combine<<<40, 256, 0, stream>>>(tpart, out);
}

// Round 8
// 48.903 us; speedup vs baseline: 4.7202x; 1.4619x over previous
//
#include <hip/hip_runtime.h>
#include <cstdint>

#define B8   8
#define DIN  1024
#define NH1  2048
#define NH2  1024
#define NOUT 5120

__device__ __forceinline__ float4 ld4(const float* p) {
  return *reinterpret_cast<const float4*>(p);
}
__device__ __forceinline__ void st4(float* p, float4 v) {
  *reinterpret_cast<float4*>(p) = v;
}

// C_parts[kb][8][N] = A[8, k0:k0+KC] @ W[k0:k0+KC, :]   (partial over K-chunk)
// A source: raw input (NPART==0) or sum of NPART partials + bias (+ReLU).
// The staged (finalized) A chunk is optionally written out (features).
template<int K, int N, int KSPLIT, int NPART, bool RELU_IN, bool WRITE_STAGE>
__global__ __launch_bounds__(256)
void gemm8(const float* __restrict__ Asrc, const float* __restrict__ bias_in,
           const float* __restrict__ W, float* __restrict__ Cparts,
           float* __restrict__ stage_out)
{
  constexpr int KC    = K / KSPLIT;   // k-chunk per block
  constexpr int KC4   = KC / 4;
  constexpr int NCOLB = N / 64;       // 64 output cols per block
  constexpr int KT    = KC / 16;      // k elements per thread

  __shared__ float A_lds[8][KC];      // <= 8 KB
  __shared__ float red[16][8][64];    // 32 KB

  const int tid = threadIdx.x;
  const int kb  = blockIdx.x / NCOLB;
  const int cb  = blockIdx.x % NCOLB;
  const int k0  = kb * KC;

  // ---- stage A chunk into LDS (finalize previous stage: sum partials + bias + relu)
  for (int e = tid; e < 8 * KC4; e += 256) {
    const int b = e / KC4, k4 = e - b * KC4;
    float4 v;
    if constexpr (NPART == 0) {
      v = ld4(&Asrc[(size_t)b * K + k0 + 4 * k4]);
    } else {
      v = ld4(&bias_in[k0 + 4 * k4]);
      #pragma unroll
      for (int p = 0; p < NPART; ++p) {
        float4 t = ld4(&Asrc[((size_t)p * 8 + b) * K + k0 + 4 * k4]);
        v.x += t.x; v.y += t.y; v.z += t.z; v.w += t.w;
      }
      if constexpr (RELU_IN) {
        v.x = fmaxf(v.x, 0.f); v.y = fmaxf(v.y, 0.f);
        v.z = fmaxf(v.z, 0.f); v.w = fmaxf(v.w, 0.f);
      }
    }
    st4(&A_lds[b][4 * k4], v);
    if constexpr (WRITE_STAGE) {
      if (cb == 0) st4(&stage_out[(size_t)b * K + k0 + 4 * k4], v);
    }
  }
  __syncthreads();

  // ---- main loop: 16 col-groups (float4) x 16 k-slices
  const int g  = tid & 15, ks = tid >> 4;
  const int c0 = cb * 64 + g * 4;
  float4 acc[8];
  #pragma unroll
  for (int b = 0; b < 8; ++b) acc[b] = make_float4(0.f, 0.f, 0.f, 0.f);

  const float* Wp = &W[(size_t)(k0 + ks * KT) * N + c0];
  #pragma unroll
  for (int i = 0; i < KT; i += 4) {
    const float4 w0 = ld4(Wp + (size_t)(i + 0) * N);
    const float4 w1 = ld4(Wp + (size_t)(i + 1) * N);
    const float4 w2 = ld4(Wp + (size_t)(i + 2) * N);
    const float4 w3 = ld4(Wp + (size_t)(i + 3) * N);
    const int kk = ks * KT + i;
    #pragma unroll
    for (int b = 0; b < 8; ++b) {
      const float4 a = ld4(&A_lds[b][kk]);   // broadcast within 16-lane group
      acc[b].x += a.x * w0.x + a.y * w1.x + a.z * w2.x + a.w * w3.x;
      acc[b].y += a.x * w0.y + a.y * w1.y + a.z * w2.y + a.w * w3.y;
      acc[b].z += a.x * w0.z + a.y * w1.z + a.z * w2.z + a.w * w3.z;
      acc[b].w += a.x * w0.w + a.y * w1.w + a.z * w2.w + a.w * w3.w;
    }
  }

  // ---- reduce the 16 k-slices through LDS
  __syncthreads();
  #pragma unroll
  for (int b = 0; b < 8; ++b) st4(&red[ks][b][g * 4], acc[b]);
  __syncthreads();

  for (int p = tid; p < 512; p += 256) {
    const int c = p & 63, b = p >> 6;
    float s = 0.f;
    #pragma unroll
    for (int j = 0; j < 16; ++j) s += red[j][b][c];
    Cparts[((size_t)kb * 8 + b) * N + cb * 64 + c] = s;
  }
}

// logits[8][5120] = sum of 4 partials + b3
__global__ __launch_bounds__(256)
void finalize_logits(const float* __restrict__ parts, const float* __restrict__ b3,
                     float* __restrict__ logits)
{
  const int i  = blockIdx.x * 256 + threadIdx.x;   // 10240 float4s, grid exact
  const int b  = i / 1280, k4 = i - b * 1280;
  float4 v = ld4(&b3[4 * k4]);
  #pragma unroll
  for (int p = 0; p < 4; ++p) {
    const float4 t = ld4(&parts[((size_t)p * 8 + b) * NOUT + 4 * k4]);
    v.x += t.x; v.y += t.y; v.z += t.z; v.w += t.w;
  }
  st4(&logits[(size_t)b * NOUT + 4 * k4], v);
}

// out[b][o] = max_k logits[b][k] * CM[o][k]
// DUMB AND OCCUPANT: 2 CM rows per wave, rolled j-loop, no LDS, no barriers,
// no manual buffering. Live state ~50 VGPR -> high occupancy; the 2 KB of
// CM loads stay in flight under the L1-hot logits loads + VALU of each
// iteration (TLP does the pipelining, not the source). 640 blocks x 4 waves
// x 2 rows = 5120 rows. Direct write, no partials.
__global__ __launch_bounds__(256)
void tropical2r(const float* __restrict__ logits, const float* __restrict__ CM,
                float* __restrict__ out)
{
  const int tid = threadIdx.x;
  const int w   = tid >> 6;      // wave 0..3
  const int l   = tid & 63;      // lane
  const int o0  = (blockIdx.x * 4 + w) * 2;   // this wave's 2 rows

  const float* cm0 = &CM[(size_t)(o0 + 0) * NOUT + 4 * l];
  const float* cm1 = &CM[(size_t)(o0 + 1) * NOUT + 4 * l];
  const float* lg  = &logits[4 * l];

  float pmax0[8], pmax1[8];
  #pragma unroll
  for (int b = 0; b < 8; ++b) { pmax0[b] = -3.402823466e38f; pmax1[b] = -3.402823466e38f; }

  for (int j = 0; j < 20; ++j) {           // rolled: let the compiler schedule
    const int off = 256 * j;               // 64 lanes * float4
    const float4 c0 = ld4(cm0 + off);
    const float4 c1 = ld4(cm1 + off);
    #pragma unroll
    for (int b = 0; b < 8; ++b) {
      const float4 lv = ld4(lg + (size_t)b * NOUT + off);
      const float a0 = fmaxf(lv.x * c0.x, lv.y * c0.y);
      const float a1 = fmaxf(lv.z * c0.z, lv.w * c0.w);
      pmax0[b] = fmaxf(pmax0[b], fmaxf(a0, a1));
      const float b0 = fmaxf(lv.x * c1.x, lv.y * c1.y);
      const float b1 = fmaxf(lv.z * c1.z, lv.w * c1.w);
      pmax1[b] = fmaxf(pmax1[b], fmaxf(b0, b1));
    }
  }

  // cross-lane max reduce; lane 0 writes both rows
  #pragma unroll
  for (int b = 0; b < 8; ++b) {
    float v0 = pmax0[b], v1 = pmax1[b];
    for (int m = 32; m; m >>= 1) {
      v0 = fmaxf(v0, __shfl_xor(v0, m));
      v1 = fmaxf(v1, __shfl_xor(v1, m));
    }
    if (l == 0) {
      out[(size_t)b * NOUT + o0 + 0] = v0;
      out[(size_t)b * NOUT + o0 + 1] = v1;
    }
  }
}

extern "C" void kernel_launch(void* const* d_in, const int* in_sizes, int n_in,
                              void* d_out, int out_size, void* d_ws, size_t ws_size,
                              hipStream_t stream)
{
  const float* x  = (const float*)d_in[0];
  const float* W1 = (const float*)d_in[1];
  const float* b1 = (const float*)d_in[2];
  const float* W2 = (const float*)d_in[3];
  const float* b2 = (const float*)d_in[4];
  const float* W3 = (const float*)d_in[5];
  const float* b3 = (const float*)d_in[6];
  const float* CM = (const float*)d_in[7];

  float* out  = (float*)d_out;            // [8][5120]
  float* feat = out + B8 * NOUT;          // [8][1024]

  float* ws      = (float*)d_ws;
  float* parts1  = ws;                      // [ 8][8][2048] = 131072 f
  float* parts2  = parts1 + 8  * 8 * NH1;   // [16][8][1024] = 131072 f
  float* parts3  = parts2 + 16 * 8 * NH2;   // [ 4][8][5120] = 163840 f
  float* logits  = parts3 + 4  * 8 * NOUT;  // [8][5120]     =  40960 f

  // h1 partials: x[8,1024] @ W1[1024,2048], K split 8 -> 256 blocks
  gemm8<DIN, NH1, 8, 0, false, false><<<256, 256, 0, stream>>>(x, nullptr, W1, parts1, nullptr);
  // h2 partials: relu(sum parts1 + b1) @ W2[2048,1024], K split 16 -> 256 blocks
  gemm8<NH1, NH2, 16, 8, true, false><<<256, 256, 0, stream>>>(parts1, b1, W2, parts2, nullptr);
  // logits partials: relu(sum parts2 + b2) @ W3[1024,5120], K split 4 -> 320 blocks
  // (staged A == features; written by cb==0 blocks)
  gemm8<NH2, NOUT, 4, 16, true, true><<<320, 256, 0, stream>>>(parts2, b2, W3, parts3, feat);
  // logits = sum parts3 + b3
  finalize_logits<<<40, 256, 0, stream>>>(parts3, b3, logits);
  // tropical max-product: 640 blocks x 4 waves x 2 rows, rolled streaming
  tropical2r<<<640, 256, 0, stream>>>(logits, CM, out);
}